// Round 5
// baseline (65914.703 us; speedup 1.0000x reference)
//
#include <hip/hip_runtime.h>
#include <hip/hip_bf16.h>
#include <math.h>

// Problem constants
#define T_STEPS 8192
#define HDIM    1024
#define GWS     256     // scan workgroups: 4 outputs each, all 256 CUs

// Workspace layout (bytes)
#define OFF_REV   ((size_t)0)                         // 8192*64*4   = 2 MB
#define OFF_X1    ((size_t)2097152)                   // 8192*512*4  = 16 MB (reused as slots after gemm2)
#define OFF_B     ((size_t)18874368)                  // x2 then hs: 8192*1024*4 = 32 MB
#define OFF_C     ((size_t)52428800)                  // xp then y1: 8192*3072*4 = 96 MB
#define WS_NEEDED ((size_t)153092096)

typedef float f4 __attribute__((ext_vector_type(4)));
typedef float f2 __attribute__((ext_vector_type(2)));

__device__ inline float sigm(float x)   { return 1.0f / (1.0f + __expf(-x)); }
__device__ inline float tanh_f(float x) { float e = __expf(2.0f * x); return 1.0f - 2.0f / (e + 1.0f); }

// Publish {h, tag} as one 8B device-scope atomic exchange: executes at the
// MALL (Infinity Cache) and leaves the line resident there — no DRAM
// write-through, and subsequent sc0sc1 poll loads hit MALL, not HBM.
__device__ inline void publish_slot(f2* p, float h, unsigned tag) {
    unsigned long long u = ((unsigned long long)tag << 32)
                         | (unsigned long long)__float_as_uint(h);
    (void)__hip_atomic_exchange((unsigned long long*)p, u,
                                __ATOMIC_RELAXED, __HIP_MEMORY_SCOPE_AGENT);
}

// ---------------------------------------------------------------------------
// build rev: rev[t][0:32]=weather[T-1-t], rev[t][32:64]=infect[T-1-t]
// ---------------------------------------------------------------------------
__global__ void build_rev(const float* __restrict__ wea, const float* __restrict__ inf,
                          float* __restrict__ rev) {
    int idx = blockIdx.x * blockDim.x + threadIdx.x;   // over T*64
    if (idx >= T_STEPS * 64) return;
    int t = idx >> 6, c = idx & 63;
    int ts = T_STEPS - 1 - t;
    rev[idx] = (c < 32) ? wea[ts * 32 + c] : inf[ts * 32 + (c - 32)];
}

// ---------------------------------------------------------------------------
// seed slots parity 0 with h_init, tag 0
// ---------------------------------------------------------------------------
__global__ void seed_slots(const float* __restrict__ h0, f2* __restrict__ slots) {
    int i = blockIdx.x * blockDim.x + threadIdx.x;
    if (i < HDIM) publish_slot(&slots[i], h0[i], 0u);
}

// ---------------------------------------------------------------------------
// Tiled f32 GEMM: C[M,N] = act(A[M,K] @ W[N,K]^T + bias[N]); BM=BN=64, BK=32
// ---------------------------------------------------------------------------
__global__ __launch_bounds__(256) void gemm_bias_act(
    const float* __restrict__ A, const float* __restrict__ W,
    const float* __restrict__ bias, float* __restrict__ C,
    int M, int N, int K, int relu)
{
    __shared__ float As[32][68];
    __shared__ float Ws[32][68];
    const int tid = threadIdx.x;
    const int tx = tid & 15, ty = tid >> 4;
    const int bm = blockIdx.y, bn = blockIdx.x;
    const float* Ab = A + (size_t)bm * 64 * K;
    const float* Wb = W + (size_t)bn * 64 * K;
    float acc[4][4] = {};

    for (int k0 = 0; k0 < K; k0 += 32) {
#pragma unroll
        for (int q = 0; q < 2; ++q) {
            int idx = tid * 2 + q;           // 0..511
            int row = idx >> 3;              // 0..63
            int kc  = (idx & 7) << 2;        // 0..28
            float4 av = *(const float4*)(Ab + (size_t)row * K + k0 + kc);
            As[kc + 0][row] = av.x; As[kc + 1][row] = av.y;
            As[kc + 2][row] = av.z; As[kc + 3][row] = av.w;
            float4 wv = *(const float4*)(Wb + (size_t)row * K + k0 + kc);
            Ws[kc + 0][row] = wv.x; Ws[kc + 1][row] = wv.y;
            Ws[kc + 2][row] = wv.z; Ws[kc + 3][row] = wv.w;
        }
        __syncthreads();
#pragma unroll
        for (int k = 0; k < 32; ++k) {
            float4 a = *(const float4*)&As[k][ty << 2];
            float4 b = *(const float4*)&Ws[k][tx << 2];
            acc[0][0] += a.x*b.x; acc[0][1] += a.x*b.y; acc[0][2] += a.x*b.z; acc[0][3] += a.x*b.w;
            acc[1][0] += a.y*b.x; acc[1][1] += a.y*b.y; acc[1][2] += a.y*b.z; acc[1][3] += a.y*b.w;
            acc[2][0] += a.z*b.x; acc[2][1] += a.z*b.y; acc[2][2] += a.z*b.z; acc[2][3] += a.z*b.w;
            acc[3][0] += a.w*b.x; acc[3][1] += a.w*b.y; acc[3][2] += a.w*b.z; acc[3][3] += a.w*b.w;
        }
        __syncthreads();
    }

    int m0 = bm * 64 + (ty << 2), n0 = bn * 64 + (tx << 2);
    float4 bv = *(const float4*)(bias + n0);
#pragma unroll
    for (int r = 0; r < 4; ++r) {
        float4 o;
        o.x = acc[r][0] + bv.x; o.y = acc[r][1] + bv.y;
        o.z = acc[r][2] + bv.z; o.w = acc[r][3] + bv.w;
        if (relu) {
            o.x = fmaxf(o.x, 0.f); o.y = fmaxf(o.y, 0.f);
            o.z = fmaxf(o.z, 0.f); o.w = fmaxf(o.w, 0.f);
        }
        *(float4*)(C + (size_t)(m0 + r) * N + n0) = o;
    }
}

// ---------------------------------------------------------------------------
// Gather-wave poll: lane l covers slot pairs {2l+128j, 2l+128j+1}, j=0..7,
// via 8 concurrent dwordx4 sc0sc1 loads; retry until every tag == want;
// then deposit h into LDS.
// ---------------------------------------------------------------------------
__device__ inline void gather_poll(const f2* __restrict__ slotp, int l,
                                   unsigned want, float* __restrict__ hdst) {
    const char* b1 = (const char*)(slotp + 2 * l);
    const char* b2 = b1 + 4096;
    f4 v[8];
    for (;;) {
        asm volatile(
            "global_load_dwordx4 %0, %8, off sc0 sc1\n\t"
            "global_load_dwordx4 %1, %8, off offset:1024 sc0 sc1\n\t"
            "global_load_dwordx4 %2, %8, off offset:2048 sc0 sc1\n\t"
            "global_load_dwordx4 %3, %8, off offset:3072 sc0 sc1\n\t"
            "global_load_dwordx4 %4, %9, off sc0 sc1\n\t"
            "global_load_dwordx4 %5, %9, off offset:1024 sc0 sc1\n\t"
            "global_load_dwordx4 %6, %9, off offset:2048 sc0 sc1\n\t"
            "global_load_dwordx4 %7, %9, off offset:3072 sc0 sc1\n\t"
            "s_waitcnt vmcnt(0)"
            : "=v"(v[0]), "=v"(v[1]), "=v"(v[2]), "=v"(v[3]),
              "=v"(v[4]), "=v"(v[5]), "=v"(v[6]), "=v"(v[7])
            : "v"(b1), "v"(b2)
            : "memory");
        int ok = 1;
#pragma unroll
        for (int j = 0; j < 8; ++j) {
            ok &= (__float_as_uint(v[j].y) == want);
            ok &= (__float_as_uint(v[j].w) == want);
        }
        if (__all(ok)) break;
    }
#pragma unroll
    for (int j = 0; j < 8; ++j) {
        float2 t; t.x = v[j].x; t.y = v[j].z;
        *(float2*)&hdst[2 * l + 128 * j] = t;
    }
}

// ---------------------------------------------------------------------------
// GRU scan. 256 WGs x 320 thr: waves 0-3 compute (1 output each, 3 weight
// rows staged in LDS), wave 4 gathers h via slot polling into LDS.
// Tags: read tag t (parity t&1), publish tag t+1 (parity (t+1)&1).
// ---------------------------------------------------------------------------
__global__ __launch_bounds__(320, 1) void gru_scan(
    const float* __restrict__ whh,   // 3072x1024
    const float* __restrict__ bhh,   // 3072
    const float* __restrict__ xp,    // 8192x3072 (includes bih)
    f2* __restrict__ slots,          // [2][1024] {h, tag}
    float* __restrict__ hs)          // 8192x1024; hs[0]=h_enc at end
{
    __shared__ float wlds[12][HDIM];   // 48 KB: wave w rows at [3w..3w+2]
    __shared__ float h_sh[2][HDIM];    // 8 KB
    const int g = blockIdx.x, tid = threadIdx.x;
    const int w = tid >> 6, l = tid & 63;

    if (w == 4) {
        // ---- gather wave ----
#pragma unroll 1
        for (int t = 0; t < T_STEPS; ++t) {
            const int p = t & 1;
            gather_poll(slots + (size_t)p * HDIM, l, (unsigned)t, h_sh[p]);
            __syncthreads();
        }
        return;
    }

    // ---- compute wave: owns output idx ----
    const int idx = 4 * g + w;
    // stage this wave's 3 rows into LDS (own rows only -> no barrier needed)
#pragma unroll
    for (int r = 0; r < 3; ++r) {
        const float* wr = whh + (size_t)(r * HDIM + idx) * HDIM + 4 * l;
#pragma unroll
        for (int j = 0; j < 4; ++j)
            *(f4*)&wlds[3 * w + r][256 * j + 4 * l] = *(const f4*)(wr + 256 * j);
    }

    const float b0 = bhh[idx], b1 = bhh[HDIM + idx], b2 = bhh[2 * HDIM + idx];
    float xv0 = xp[idx], xv1 = xp[HDIM + idx], xv2 = xp[2 * HDIM + idx];

#pragma unroll 1
    for (int t = 0; t < T_STEPS; ++t) {
        const int p = t & 1;
        __syncthreads();                       // gather finished writing h_sh[p]

        f4 h4[4];
#pragma unroll
        for (int j = 0; j < 4; ++j) h4[j] = *(const f4*)&h_sh[p][256 * j + 4 * l];

        f4 a0 = {0.f, 0.f, 0.f, 0.f}, a1 = a0, a2 = a0;
#pragma unroll
        for (int j = 0; j < 4; ++j) {
            a0 += (*(const f4*)&wlds[3 * w + 0][256 * j + 4 * l]) * h4[j];
            a1 += (*(const f4*)&wlds[3 * w + 1][256 * j + 4 * l]) * h4[j];
            a2 += (*(const f4*)&wlds[3 * w + 2][256 * j + 4 * l]) * h4[j];
        }
        float r0 = a0.x + a0.y + a0.z + a0.w;
        float r1 = a1.x + a1.y + a1.z + a1.w;
        float r2 = a2.x + a2.y + a2.z + a2.w;
#pragma unroll
        for (int off = 32; off > 0; off >>= 1) {
            r0 += __shfl_xor(r0, off, 64);
            r1 += __shfl_xor(r1, off, 64);
            r2 += __shfl_xor(r2, off, 64);
        }

        // gates (all lanes redundantly; lane 0 publishes)
        float r_ = sigm(xv0 + r0 + b0);
        float z_ = sigm(xv1 + r1 + b1);
        float n_ = tanh_f(xv2 + r_ * (r2 + b2));
        float hn = (1.0f - z_) * n_ + z_ * h_sh[p][idx];

        if (l == 0) {
            unsigned pub = (unsigned)(t + 1);
            publish_slot(slots + (size_t)(pub & 1) * HDIM + idx, hn, pub);
            if (t == T_STEPS - 1) hs[idx] = hn;
        }
        if (t + 1 < T_STEPS) {
            const float* xq = xp + (size_t)(t + 1) * (3 * HDIM);
            xv0 = xq[idx]; xv1 = xq[HDIM + idx]; xv2 = xq[2 * HDIM + idx];
        }
    }
}

// ---------------------------------------------------------------------------
// LSTM-like decoder scan: h_new = o*tanh(i*g); forget rows [H,2H) dead.
// Continues tag sequence: reads 8191+s, publishes 8192+s.
// ---------------------------------------------------------------------------
__global__ __launch_bounds__(320, 1) void lstm_scan(
    const float* __restrict__ wih,   // 4096x1024
    const float* __restrict__ bih,   // 4096
    const float* __restrict__ bhh,   // 4096
    f2* __restrict__ slots,          // [2][1024]
    float* __restrict__ hs)          // 8192x1024; write hs[1..T-1]
{
    __shared__ float wlds[12][HDIM];
    __shared__ float h_sh[2][HDIM];
    const int g = blockIdx.x, tid = threadIdx.x;
    const int w = tid >> 6, l = tid & 63;

    if (w == 4) {
#pragma unroll 1
        for (int s = 1; s < T_STEPS; ++s) {
            const unsigned want = (unsigned)(8191 + s);
            const int p = (int)(want & 1);
            gather_poll(slots + (size_t)p * HDIM, l, want, h_sh[p]);
            __syncthreads();
        }
        return;
    }

    const int idx = 4 * g + w;
    const int rows[3] = { idx, 2 * HDIM + idx, 3 * HDIM + idx };
#pragma unroll
    for (int r = 0; r < 3; ++r) {
        const float* wr = wih + (size_t)rows[r] * HDIM + 4 * l;
#pragma unroll
        for (int j = 0; j < 4; ++j)
            *(f4*)&wlds[3 * w + r][256 * j + 4 * l] = *(const f4*)(wr + 256 * j);
    }

    const float b0 = bih[rows[0]] + bhh[rows[0]];
    const float b1 = bih[rows[1]] + bhh[rows[1]];
    const float b2 = bih[rows[2]] + bhh[rows[2]];

#pragma unroll 1
    for (int s = 1; s < T_STEPS; ++s) {
        const unsigned want = (unsigned)(8191 + s);
        const int p = (int)(want & 1);
        __syncthreads();

        f4 h4[4];
#pragma unroll
        for (int j = 0; j < 4; ++j) h4[j] = *(const f4*)&h_sh[p][256 * j + 4 * l];

        f4 a0 = {0.f, 0.f, 0.f, 0.f}, a1 = a0, a2 = a0;
#pragma unroll
        for (int j = 0; j < 4; ++j) {
            a0 += (*(const f4*)&wlds[3 * w + 0][256 * j + 4 * l]) * h4[j];
            a1 += (*(const f4*)&wlds[3 * w + 1][256 * j + 4 * l]) * h4[j];
            a2 += (*(const f4*)&wlds[3 * w + 2][256 * j + 4 * l]) * h4[j];
        }
        float r0 = a0.x + a0.y + a0.z + a0.w;
        float r1 = a1.x + a1.y + a1.z + a1.w;
        float r2 = a2.x + a2.y + a2.z + a2.w;
#pragma unroll
        for (int off = 32; off > 0; off >>= 1) {
            r0 += __shfl_xor(r0, off, 64);
            r1 += __shfl_xor(r1, off, 64);
            r2 += __shfl_xor(r2, off, 64);
        }

        float i_ = sigm(r0 + b0);
        float g_ = tanh_f(r1 + b1);
        float o_ = sigm(r2 + b2);
        float hn = o_ * tanh_f(i_ * g_);

        if (l == 0) {
            unsigned pub = want + 1;
            publish_slot(slots + (size_t)(pub & 1) * HDIM + idx, hn, pub);
            hs[(size_t)s * HDIM + idx] = hn;
        }
    }
}

// ---------------------------------------------------------------------------
// Final tiny GEMM: out[t][0:8] = y1[t] @ dec_w2^T + dec_b2, one wave per t
// ---------------------------------------------------------------------------
__global__ __launch_bounds__(256) void dec2_kernel(
    const float* __restrict__ y1,    // 8192x512
    const float* __restrict__ w2,    // 8x512
    const float* __restrict__ b2,    // 8
    float* __restrict__ out)         // 8192x8
{
    const int w = threadIdx.x >> 6, l = threadIdx.x & 63;
    const int t = blockIdx.x * 4 + w;
    const float* yr = y1 + (size_t)t * 512;
    float yv[8];
#pragma unroll
    for (int j = 0; j < 8; ++j) yv[j] = yr[l + 64 * j];
    float o[8];
#pragma unroll
    for (int n = 0; n < 8; ++n) {
        const float* wr = w2 + n * 512;
        float s = 0.f;
#pragma unroll
        for (int j = 0; j < 8; ++j) s += yv[j] * wr[l + 64 * j];
#pragma unroll
        for (int off = 32; off > 0; off >>= 1) s += __shfl_xor(s, off, 64);
        o[n] = s;
    }
    if (l == 0) {
#pragma unroll
        for (int n = 0; n < 8; ++n) out[(size_t)t * 8 + n] = o[n] + b2[n];
    }
}

// ---------------------------------------------------------------------------
extern "C" void kernel_launch(void* const* d_in, const int* in_sizes, int n_in,
                              void* d_out, int out_size, void* d_ws, size_t ws_size,
                              hipStream_t stream)
{
    const float* wea      = (const float*)d_in[0];
    const float* inf      = (const float*)d_in[1];
    const float* h_init   = (const float*)d_in[3];
    const float* enc_w1   = (const float*)d_in[4];
    const float* enc_b1   = (const float*)d_in[5];
    const float* enc_w2   = (const float*)d_in[6];
    const float* enc_b2   = (const float*)d_in[7];
    const float* gru_wih  = (const float*)d_in[8];
    const float* gru_whh  = (const float*)d_in[9];
    const float* gru_bih  = (const float*)d_in[10];
    const float* gru_bhh  = (const float*)d_in[11];
    const float* lstm_wih = (const float*)d_in[12];
    const float* lstm_bih = (const float*)d_in[13];
    const float* lstm_bhh = (const float*)d_in[14];
    const float* dec_w1   = (const float*)d_in[15];
    const float* dec_b1   = (const float*)d_in[16];
    const float* dec_w2   = (const float*)d_in[17];
    const float* dec_b2   = (const float*)d_in[18];

    if (ws_size < WS_NEEDED) return;

    char* ws = (char*)d_ws;
    float* rev   = (float*)(ws + OFF_REV);
    float* x1    = (float*)(ws + OFF_X1);
    float* x2    = (float*)(ws + OFF_B);    // later reused as hs
    float* hs    = (float*)(ws + OFF_B);
    float* xp    = (float*)(ws + OFF_C);    // later reused as y1
    float* y1    = (float*)(ws + OFF_C);
    f2*    slots = (f2*)(ws + OFF_X1);      // x1 dead after gemm2; 16 KB

    build_rev<<<(T_STEPS * 64) / 256, 256, 0, stream>>>(wea, inf, rev);

    // encoder
    gemm_bias_act<<<dim3(8, 128), 256, 0, stream>>>(rev, enc_w1, enc_b1, x1,
                                                    T_STEPS, 512, 64, 1);
    gemm_bias_act<<<dim3(16, 128), 256, 0, stream>>>(x1, enc_w2, enc_b2, x2,
                                                     T_STEPS, 1024, 512, 1);
    // GRU input projection xp = x2 @ gru_wih^T + gru_bih
    gemm_bias_act<<<dim3(48, 128), 256, 0, stream>>>(x2, gru_wih, gru_bih, xp,
                                                     T_STEPS, 3 * HDIM, HDIM, 0);
    // seed slot buffer (x1 region now dead) and run the scans
    seed_slots<<<4, 256, 0, stream>>>(h_init, slots);
    gru_scan<<<GWS, 320, 0, stream>>>(gru_whh, gru_bhh, xp, slots, hs);
    lstm_scan<<<GWS, 320, 0, stream>>>(lstm_wih, lstm_bih, lstm_bhh, slots, hs);

    // decoder
    gemm_bias_act<<<dim3(8, 128), 256, 0, stream>>>(hs, dec_w1, dec_b1, y1,
                                                    T_STEPS, 512, HDIM, 1);
    dec2_kernel<<<T_STEPS / 4, 256, 0, stream>>>(y1, dec_w2, dec_b2, (float*)d_out);
}

// Round 6
// 56561.682 us; speedup vs baseline: 1.1654x; 1.1654x over previous
//
#include <hip/hip_runtime.h>
#include <hip/hip_bf16.h>
#include <math.h>

// Problem constants
#define T_STEPS 8192
#define HDIM    1024
#define GWS     128     // scan workgroups: 8 outputs each

// Workspace layout (bytes)
#define OFF_REV   ((size_t)0)                         // 8192*64*4   = 2 MB
#define OFF_X1    ((size_t)2097152)                   // 8192*512*4  = 16 MB (reused as slots after gemm2)
#define OFF_B     ((size_t)18874368)                  // x2 then hs: 8192*1024*4 = 32 MB
#define OFF_C     ((size_t)52428800)                  // xp then y1: 8192*3072*4 = 96 MB
#define WS_NEEDED ((size_t)153092096)

typedef float f4 __attribute__((ext_vector_type(4)));
typedef float f2 __attribute__((ext_vector_type(2)));

__device__ inline float sigm(float x)   { return 1.0f / (1.0f + __expf(-x)); }
__device__ inline float tanh_f(float x) { float e = __expf(2.0f * x); return 1.0f - 2.0f / (e + 1.0f); }

// Publish {h, tag} as one 8B device-scope atomic exchange at the coherence pt.
__device__ inline void publish_slot(f2* p, float h, unsigned tag) {
    unsigned long long u = ((unsigned long long)tag << 32)
                         | (unsigned long long)__float_as_uint(h);
    (void)__hip_atomic_exchange((unsigned long long*)p, u,
                                __ATOMIC_RELAXED, __HIP_MEMORY_SCOPE_AGENT);
}

// Poll 2 adjacent slots {h0,tag0,h1,tag1} with one coherent dwordx4.
// Whole wave retries until every lane sees both tags == want.
__device__ inline f4 poll2(const f2* __restrict__ p, unsigned want) {
    f4 v;
    for (;;) {
        asm volatile("global_load_dwordx4 %0, %1, off sc0 sc1\n\ts_waitcnt vmcnt(0)"
                     : "=v"(v) : "v"(p) : "memory");
        int ok = (__float_as_uint(v.y) == want) & (__float_as_uint(v.w) == want);
        if (__all(ok)) return v;
        __builtin_amdgcn_s_sleep(1);
    }
}

// ---------------------------------------------------------------------------
// build rev: rev[t][0:32]=weather[T-1-t], rev[t][32:64]=infect[T-1-t]
// ---------------------------------------------------------------------------
__global__ void build_rev(const float* __restrict__ wea, const float* __restrict__ inf,
                          float* __restrict__ rev) {
    int idx = blockIdx.x * blockDim.x + threadIdx.x;   // over T*64
    if (idx >= T_STEPS * 64) return;
    int t = idx >> 6, c = idx & 63;
    int ts = T_STEPS - 1 - t;
    rev[idx] = (c < 32) ? wea[ts * 32 + c] : inf[ts * 32 + (c - 32)];
}

// ---------------------------------------------------------------------------
// seed: parity0 = {h_init, tag 0}; parity1 = {0, tag 0} (never matches a want)
// ---------------------------------------------------------------------------
__global__ void seed_slots(const float* __restrict__ h0, f2* __restrict__ slots) {
    int i = blockIdx.x * blockDim.x + threadIdx.x;
    if (i < HDIM) {
        publish_slot(&slots[i], h0[i], 0u);
        publish_slot(&slots[HDIM + i], 0.0f, 0u);
    }
}

// ---------------------------------------------------------------------------
// Tiled f32 GEMM: C[M,N] = act(A[M,K] @ W[N,K]^T + bias[N]); BM=BN=64, BK=32
// ---------------------------------------------------------------------------
__global__ __launch_bounds__(256) void gemm_bias_act(
    const float* __restrict__ A, const float* __restrict__ W,
    const float* __restrict__ bias, float* __restrict__ C,
    int M, int N, int K, int relu)
{
    __shared__ float As[32][68];
    __shared__ float Ws[32][68];
    const int tid = threadIdx.x;
    const int tx = tid & 15, ty = tid >> 4;
    const int bm = blockIdx.y, bn = blockIdx.x;
    const float* Ab = A + (size_t)bm * 64 * K;
    const float* Wb = W + (size_t)bn * 64 * K;
    float acc[4][4] = {};

    for (int k0 = 0; k0 < K; k0 += 32) {
#pragma unroll
        for (int q = 0; q < 2; ++q) {
            int idx = tid * 2 + q;           // 0..511
            int row = idx >> 3;              // 0..63
            int kc  = (idx & 7) << 2;        // 0..28
            float4 av = *(const float4*)(Ab + (size_t)row * K + k0 + kc);
            As[kc + 0][row] = av.x; As[kc + 1][row] = av.y;
            As[kc + 2][row] = av.z; As[kc + 3][row] = av.w;
            float4 wv = *(const float4*)(Wb + (size_t)row * K + k0 + kc);
            Ws[kc + 0][row] = wv.x; Ws[kc + 1][row] = wv.y;
            Ws[kc + 2][row] = wv.z; Ws[kc + 3][row] = wv.w;
        }
        __syncthreads();
#pragma unroll
        for (int k = 0; k < 32; ++k) {
            float4 a = *(const float4*)&As[k][ty << 2];
            float4 b = *(const float4*)&Ws[k][tx << 2];
            acc[0][0] += a.x*b.x; acc[0][1] += a.x*b.y; acc[0][2] += a.x*b.z; acc[0][3] += a.x*b.w;
            acc[1][0] += a.y*b.x; acc[1][1] += a.y*b.y; acc[1][2] += a.y*b.z; acc[1][3] += a.y*b.w;
            acc[2][0] += a.z*b.x; acc[2][1] += a.z*b.y; acc[2][2] += a.z*b.z; acc[2][3] += a.z*b.w;
            acc[3][0] += a.w*b.x; acc[3][1] += a.w*b.y; acc[3][2] += a.w*b.z; acc[3][3] += a.w*b.w;
        }
        __syncthreads();
    }

    int m0 = bm * 64 + (ty << 2), n0 = bn * 64 + (tx << 2);
    float4 bv = *(const float4*)(bias + n0);
#pragma unroll
    for (int r = 0; r < 4; ++r) {
        float4 o;
        o.x = acc[r][0] + bv.x; o.y = acc[r][1] + bv.y;
        o.z = acc[r][2] + bv.z; o.w = acc[r][3] + bv.w;
        if (relu) {
            o.x = fmaxf(o.x, 0.f); o.y = fmaxf(o.y, 0.f);
            o.z = fmaxf(o.z, 0.f); o.w = fmaxf(o.w, 0.f);
        }
        *(float4*)(C + (size_t)(m0 + r) * N + n0) = o;
    }
}

// ---------------------------------------------------------------------------
// GRU scan. 128 WGs x 512 thr (8 waves). Wave w computes output idx=8g+w,
// 3 whh rows in LDS (96 KB total). Every lane polls 2 slots (one dwordx4),
// deposits into LDS, one barrier, compute, lane0 publishes.
// Tags: read tag t (parity t&1), publish tag t+1 (parity (t+1)&1).
// ---------------------------------------------------------------------------
__global__ __launch_bounds__(512, 1) void gru_scan(
    const float* __restrict__ whh,   // 3072x1024
    const float* __restrict__ bhh,   // 3072
    const float* __restrict__ xp,    // 8192x3072 (includes bih)
    f2* __restrict__ slots,          // [2][1024] {h, tag}
    float* __restrict__ hs)          // 8192x1024 (only hs[0] here, by lstm)
{
    __shared__ float wlds[24][HDIM];   // 96 KB: wave w rows at [3w..3w+2]
    __shared__ float h_sh[2][HDIM];    // 8 KB
    const int g = blockIdx.x, tid = threadIdx.x;
    const int w = tid >> 6, l = tid & 63;
    const int idx = 8 * g + w;         // output this wave owns

    // stage this wave's 3 rows into LDS (own rows only -> no barrier needed)
#pragma unroll
    for (int r = 0; r < 3; ++r) {
        const float* wr = whh + (size_t)(r * HDIM + idx) * HDIM + 4 * l;
#pragma unroll
        for (int j = 0; j < 4; ++j)
            *(f4*)&wlds[3 * w + r][256 * j + 4 * l] = *(const f4*)(wr + 256 * j);
    }

    const float b0 = bhh[idx], b1 = bhh[HDIM + idx], b2 = bhh[2 * HDIM + idx];
    float xv0 = xp[idx], xv1 = xp[HDIM + idx], xv2 = xp[2 * HDIM + idx];

#pragma unroll 1
    for (int t = 0; t < T_STEPS; ++t) {
        const int p = t & 1;
        // poll my 2 slots (lane k=64w+l covers slots 2k,2k+1)
        f4 sv = poll2(slots + (size_t)p * HDIM + 2 * tid, (unsigned)t);
        *(float2*)&h_sh[p][2 * tid] = make_float2(sv.x, sv.z);
        __syncthreads();

        f4 h4[4];
#pragma unroll
        for (int j = 0; j < 4; ++j) h4[j] = *(const f4*)&h_sh[p][256 * j + 4 * l];

        f4 a0 = {0.f, 0.f, 0.f, 0.f}, a1 = a0, a2 = a0;
#pragma unroll
        for (int j = 0; j < 4; ++j) {
            a0 += (*(const f4*)&wlds[3 * w + 0][256 * j + 4 * l]) * h4[j];
            a1 += (*(const f4*)&wlds[3 * w + 1][256 * j + 4 * l]) * h4[j];
            a2 += (*(const f4*)&wlds[3 * w + 2][256 * j + 4 * l]) * h4[j];
        }
        float r0 = a0.x + a0.y + a0.z + a0.w;
        float r1 = a1.x + a1.y + a1.z + a1.w;
        float r2 = a2.x + a2.y + a2.z + a2.w;
#pragma unroll
        for (int off = 32; off > 0; off >>= 1) {
            r0 += __shfl_xor(r0, off, 64);
            r1 += __shfl_xor(r1, off, 64);
            r2 += __shfl_xor(r2, off, 64);
        }

        // gates (all lanes redundantly; lane 0 publishes)
        float r_ = sigm(xv0 + r0 + b0);
        float z_ = sigm(xv1 + r1 + b1);
        float n_ = tanh_f(xv2 + r_ * (r2 + b2));
        float hn = (1.0f - z_) * n_ + z_ * h_sh[p][idx];

        if (l == 0) {
            unsigned pub = (unsigned)(t + 1);
            publish_slot(slots + (size_t)(pub & 1) * HDIM + idx, hn, pub);
        }
        if (t + 1 < T_STEPS) {
            const float* xq = xp + (size_t)(t + 1) * (3 * HDIM);
            xv0 = xq[idx]; xv1 = xq[HDIM + idx]; xv2 = xq[2 * HDIM + idx];
        }
    }
}

// ---------------------------------------------------------------------------
// LSTM-like decoder scan: h_new = o*tanh(i*g); forget rows [H,2H) dead.
// Iteration s (1..8191): polls tag 8191+s (= h_{s-1}), publishes 8192+s.
// WG0 writes hs[s-1] coalesced from its polled registers; trailing poll
// fetches tag 16383 to write hs[8191]. hs[0]=h_enc falls out at s=1.
// ---------------------------------------------------------------------------
__global__ __launch_bounds__(512, 1) void lstm_scan(
    const float* __restrict__ wih,   // 4096x1024
    const float* __restrict__ bih,   // 4096
    const float* __restrict__ bhh,   // 4096
    f2* __restrict__ slots,          // [2][1024]
    float* __restrict__ hs)          // 8192x1024
{
    __shared__ float wlds[24][HDIM];
    __shared__ float h_sh[2][HDIM];
    const int g = blockIdx.x, tid = threadIdx.x;
    const int w = tid >> 6, l = tid & 63;
    const int idx = 8 * g + w;
    const int rows[3] = { idx, 2 * HDIM + idx, 3 * HDIM + idx };

#pragma unroll
    for (int r = 0; r < 3; ++r) {
        const float* wr = wih + (size_t)rows[r] * HDIM + 4 * l;
#pragma unroll
        for (int j = 0; j < 4; ++j)
            *(f4*)&wlds[3 * w + r][256 * j + 4 * l] = *(const f4*)(wr + 256 * j);
    }

    const float b0 = bih[rows[0]] + bhh[rows[0]];
    const float b1 = bih[rows[1]] + bhh[rows[1]];
    const float b2 = bih[rows[2]] + bhh[rows[2]];

#pragma unroll 1
    for (int s = 1; s < T_STEPS; ++s) {
        const unsigned want = (unsigned)(8191 + s);
        const int p = (int)(want & 1);
        f4 sv = poll2(slots + (size_t)p * HDIM + 2 * tid, want);
        *(float2*)&h_sh[p][2 * tid] = make_float2(sv.x, sv.z);
        if (g == 0)   // WG0 alone writes hs[s-1], fully coalesced (4 KB)
            *(float2*)&hs[(size_t)(s - 1) * HDIM + 2 * tid] = make_float2(sv.x, sv.z);
        __syncthreads();

        f4 h4[4];
#pragma unroll
        for (int j = 0; j < 4; ++j) h4[j] = *(const f4*)&h_sh[p][256 * j + 4 * l];

        f4 a0 = {0.f, 0.f, 0.f, 0.f}, a1 = a0, a2 = a0;
#pragma unroll
        for (int j = 0; j < 4; ++j) {
            a0 += (*(const f4*)&wlds[3 * w + 0][256 * j + 4 * l]) * h4[j];
            a1 += (*(const f4*)&wlds[3 * w + 1][256 * j + 4 * l]) * h4[j];
            a2 += (*(const f4*)&wlds[3 * w + 2][256 * j + 4 * l]) * h4[j];
        }
        float r0 = a0.x + a0.y + a0.z + a0.w;
        float r1 = a1.x + a1.y + a1.z + a1.w;
        float r2 = a2.x + a2.y + a2.z + a2.w;
#pragma unroll
        for (int off = 32; off > 0; off >>= 1) {
            r0 += __shfl_xor(r0, off, 64);
            r1 += __shfl_xor(r1, off, 64);
            r2 += __shfl_xor(r2, off, 64);
        }

        float i_ = sigm(r0 + b0);
        float g_ = tanh_f(r1 + b1);
        float o_ = sigm(r2 + b2);
        float hn = o_ * tanh_f(i_ * g_);

        if (l == 0)
            publish_slot(slots + (size_t)((want + 1) & 1) * HDIM + idx, hn, want + 1);
    }

    // WG0: fetch final h (tag 16383, parity 1) and write hs[8191]
    if (g == 0) {
        f4 sv = poll2(slots + (size_t)1 * HDIM + 2 * tid, (unsigned)(2 * T_STEPS - 1));
        *(float2*)&hs[(size_t)(T_STEPS - 1) * HDIM + 2 * tid] = make_float2(sv.x, sv.z);
    }
}

// ---------------------------------------------------------------------------
// Final tiny GEMM: out[t][0:8] = y1[t] @ dec_w2^T + dec_b2, one wave per t
// ---------------------------------------------------------------------------
__global__ __launch_bounds__(256) void dec2_kernel(
    const float* __restrict__ y1,    // 8192x512
    const float* __restrict__ w2,    // 8x512
    const float* __restrict__ b2,    // 8
    float* __restrict__ out)         // 8192x8
{
    const int w = threadIdx.x >> 6, l = threadIdx.x & 63;
    const int t = blockIdx.x * 4 + w;
    const float* yr = y1 + (size_t)t * 512;
    float yv[8];
#pragma unroll
    for (int j = 0; j < 8; ++j) yv[j] = yr[l + 64 * j];
    float o[8];
#pragma unroll
    for (int n = 0; n < 8; ++n) {
        const float* wr = w2 + n * 512;
        float s = 0.f;
#pragma unroll
        for (int j = 0; j < 8; ++j) s += yv[j] * wr[l + 64 * j];
#pragma unroll
        for (int off = 32; off > 0; off >>= 1) s += __shfl_xor(s, off, 64);
        o[n] = s;
    }
    if (l == 0) {
#pragma unroll
        for (int n = 0; n < 8; ++n) out[(size_t)t * 8 + n] = o[n] + b2[n];
    }
}

// ---------------------------------------------------------------------------
extern "C" void kernel_launch(void* const* d_in, const int* in_sizes, int n_in,
                              void* d_out, int out_size, void* d_ws, size_t ws_size,
                              hipStream_t stream)
{
    const float* wea      = (const float*)d_in[0];
    const float* inf      = (const float*)d_in[1];
    const float* h_init   = (const float*)d_in[3];
    const float* enc_w1   = (const float*)d_in[4];
    const float* enc_b1   = (const float*)d_in[5];
    const float* enc_w2   = (const float*)d_in[6];
    const float* enc_b2   = (const float*)d_in[7];
    const float* gru_wih  = (const float*)d_in[8];
    const float* gru_whh  = (const float*)d_in[9];
    const float* gru_bih  = (const float*)d_in[10];
    const float* gru_bhh  = (const float*)d_in[11];
    const float* lstm_wih = (const float*)d_in[12];
    const float* lstm_bih = (const float*)d_in[13];
    const float* lstm_bhh = (const float*)d_in[14];
    const float* dec_w1   = (const float*)d_in[15];
    const float* dec_b1   = (const float*)d_in[16];
    const float* dec_w2   = (const float*)d_in[17];
    const float* dec_b2   = (const float*)d_in[18];

    if (ws_size < WS_NEEDED) return;

    char* ws = (char*)d_ws;
    float* rev   = (float*)(ws + OFF_REV);
    float* x1    = (float*)(ws + OFF_X1);
    float* x2    = (float*)(ws + OFF_B);    // later reused as hs
    float* hs    = (float*)(ws + OFF_B);
    float* xp    = (float*)(ws + OFF_C);    // later reused as y1
    float* y1    = (float*)(ws + OFF_C);
    f2*    slots = (f2*)(ws + OFF_X1);      // x1 dead after gemm2; 16 KB

    build_rev<<<(T_STEPS * 64) / 256, 256, 0, stream>>>(wea, inf, rev);

    // encoder
    gemm_bias_act<<<dim3(8, 128), 256, 0, stream>>>(rev, enc_w1, enc_b1, x1,
                                                    T_STEPS, 512, 64, 1);
    gemm_bias_act<<<dim3(16, 128), 256, 0, stream>>>(x1, enc_w2, enc_b2, x2,
                                                     T_STEPS, 1024, 512, 1);
    // GRU input projection xp = x2 @ gru_wih^T + gru_bih
    gemm_bias_act<<<dim3(48, 128), 256, 0, stream>>>(x2, gru_wih, gru_bih, xp,
                                                     T_STEPS, 3 * HDIM, HDIM, 0);
    // seed slot buffer (x1 region now dead) and run the scans
    seed_slots<<<4, 256, 0, stream>>>(h_init, slots);
    gru_scan<<<GWS, 512, 0, stream>>>(gru_whh, gru_bhh, xp, slots, hs);
    lstm_scan<<<GWS, 512, 0, stream>>>(lstm_wih, lstm_bih, lstm_bhh, slots, hs);

    // decoder
    gemm_bias_act<<<dim3(8, 128), 256, 0, stream>>>(hs, dec_w1, dec_b1, y1,
                                                    T_STEPS, 512, HDIM, 1);
    dec2_kernel<<<T_STEPS / 4, 256, 0, stream>>>(y1, dec_w2, dec_b2, (float*)d_out);
}